// Round 7
// baseline (6131.989 us; speedup 1.0000x reference)
//
#include <hip/hip_runtime.h>
#include <cstdint>
#include <cstddef>

#define NEGV -1000000000.0f

// ---------- fast device math (fp32, argmax-safe) ----------
__device__ __forceinline__ float frcp(float x) { return __builtin_amdgcn_rcpf(x); }
__device__ __forceinline__ float fsigm(float x) { return frcp(1.0f + __expf(-x)); }
__device__ __forceinline__ float ftanh(float x) {
  x = fminf(x, 30.0f);
  const float e = __expf(2.0f * x);
  return (e - 1.0f) * frcp(e + 1.0f);
}

// ---------------------------------------------------------------------------
// prep1: weight repacks (unchanged from round 5/6)
// ---------------------------------------------------------------------------
__global__ __launch_bounds__(256) void prep1_k(
    const float* __restrict__ Wih, const float* __restrict__ Whh,
    const float* __restrict__ bih, const float* __restrict__ bhh,
    const float* __restrict__ Wqg, const float* __restrict__ Wm,
    const float* __restrict__ bm, const float* __restrict__ bqg,
    const float* __restrict__ Wqp, const float* __restrict__ Wrg,
    const float* __restrict__ brg, const float* __restrict__ bqp,
    float* __restrict__ WcatT, float* __restrict__ bcat,
    float* __restrict__ Wfused, float* __restrict__ bfused,
    float* __restrict__ Wgp, float* __restrict__ bgp)
{
  const int blk = blockIdx.x, t = threadIdx.x;
  if (blk == 0) {
    float acc = bqp[t];
    for (int tt = 0; tt < 256; ++tt) acc += Wqp[(t << 8) + tt] * brg[tt];
    bgp[t] = acc;
  } else if (blk <= 2048) {
    const int id = ((blk - 1) << 8) + t;      // 0..524287
    const int n = id & 1023, k = id >> 10;
    const int r = ((n & 3) << 8) + (n >> 2);
    WcatT[id] = (k < 256) ? Wih[(r << 8) + k] : Whh[(r << 8) + (k - 256)];
    if (id < 1024) {
      const int rr = ((id & 3) << 8) + (id >> 2);
      bcat[id] = bih[rr] + bhh[rr];
    }
  } else if (blk <= 2368) {
    const int id = ((blk - 2049) << 8) + t;   // 0..81919
    const int o = id / 320, j = id % 320;
    float acc = 0.f;
    for (int tt = 0; tt < 256; ++tt) acc += Wqg[(o << 8) + tt] * Wm[tt * 320 + j];
    Wfused[id] = acc;
    if (id < 256) {
      float a2 = 0.f;
      for (int tt = 0; tt < 256; ++tt) a2 += Wqg[(id << 8) + tt] * bm[tt];
      bfused[id] = a2 + bqg[id];
    }
  } else {
    const int o = blk - 2369, k = t;
    float acc = 0.f;
    for (int tt = 0; tt < 256; ++tt) acc += Wqp[(o << 8) + tt] * Wrg[(tt << 8) + k];
    Wgp[(o << 8) + k] = acc;
  }
}

// ---------------------------------------------------------------------------
// gemm256ct (unchanged): coalesced context reads, permuted stores
// ---------------------------------------------------------------------------
__device__ __forceinline__ void gemm256ct(const float* __restrict__ A,
    const float* __restrict__ W, const float* __restrict__ bias,
    float* __restrict__ C, int bx, int by, int t)
{
  __shared__ __align__(16) float As[16][68];
  __shared__ __align__(16) float Ws2[16][68];
  const int bn = bx << 6, bm = by << 6;
  const int ty = t >> 4, tx = t & 15;
  const int lr = t >> 2, lk = (t & 3) << 2;
  const int m  = bm + lr;
  const float* wrow = W + ((size_t)(bn + lr) << 8);
  float acc[4][4] = {};
  for (int k0 = 0; k0 < 256; k0 += 16) {
    const int kk = k0 + lk;
    const float4 av = *(const float4*)(A + ((size_t)m << 8) + kk);
    const float4 wv = *(const float4*)(wrow + kk);
    As[lk + 0][lr] = av.x; As[lk + 1][lr] = av.y; As[lk + 2][lr] = av.z; As[lk + 3][lr] = av.w;
    Ws2[lk + 0][lr] = wv.x; Ws2[lk + 1][lr] = wv.y; Ws2[lk + 2][lr] = wv.z; Ws2[lk + 3][lr] = wv.w;
    __syncthreads();
#pragma unroll
    for (int k = 0; k < 16; ++k) {
      const float4 a4 = *(const float4*)&As[k][ty << 2];
      const float4 w4 = *(const float4*)&Ws2[k][tx << 2];
      acc[0][0] += a4.x * w4.x; acc[0][1] += a4.x * w4.y; acc[0][2] += a4.x * w4.z; acc[0][3] += a4.x * w4.w;
      acc[1][0] += a4.y * w4.x; acc[1][1] += a4.y * w4.y; acc[1][2] += a4.y * w4.z; acc[1][3] += a4.y * w4.w;
      acc[2][0] += a4.z * w4.x; acc[2][1] += a4.z * w4.y; acc[2][2] += a4.z * w4.z; acc[2][3] += a4.z * w4.w;
      acc[3][0] += a4.w * w4.x; acc[3][1] += a4.w * w4.y; acc[3][2] += a4.w * w4.z; acc[3][3] += a4.w * w4.w;
    }
    __syncthreads();
  }
  const float4 bv = *(const float4*)(bias + bn + (tx << 2));
#pragma unroll
  for (int i = 0; i < 4; ++i) {
    const int rr = bm + (ty << 2) + i;
    const int l = rr >> 9, b = rr & 511;
    float4 o;
    o.x = acc[i][0] + bv.x; o.y = acc[i][1] + bv.y;
    o.z = acc[i][2] + bv.z; o.w = acc[i][3] + bv.w;
    *(float4*)(C + (((size_t)(b << 6) + l) << 8) + bn + (tx << 2)) = o;
  }
}

// ---------------------------------------------------------------------------
// prep2 (unchanged)
// ---------------------------------------------------------------------------
__global__ __launch_bounds__(256) void prep2_k(
    const float* __restrict__ ctxin,
    const float* __restrict__ Wrg, const float* __restrict__ brg,
    const float* __restrict__ Wrp, const float* __restrict__ brp,
    const float* __restrict__ Wgp, const float* __restrict__ bgp,
    const float* __restrict__ Wqg, const float* __restrict__ Wm,
    const float* __restrict__ Wfused, const float* __restrict__ bfused,
    const float* __restrict__ cour,
    float* __restrict__ e2g, float* __restrict__ e2p, float* __restrict__ Eg2,
    float* __restrict__ Wq1T4, float* __restrict__ qcour)
{
  const int blk = blockIdx.x, t = threadIdx.x;
  if (blk < 2048) {
    gemm256ct(ctxin, Wrg, brg, e2g, blk & 3, blk >> 2, t);
  } else if (blk < 4096) {
    const int b2 = blk - 2048;
    gemm256ct(ctxin, Wrp, brp, e2p, b2 & 3, b2 >> 2, t);
  } else if (blk < 6144) {
    const int b2 = blk - 4096;
    gemm256ct(ctxin, Wgp, bgp, Eg2, b2 & 3, b2 >> 2, t);
  } else if (blk < 6400) {
    const int o = blk - 6144;
    float acc = 0.f;
    for (int t2 = 0; t2 < 256; ++t2) acc += Wqg[(o << 8) + t2] * Wm[t2 * 320 + t];
    Wq1T4[((t >> 2) << 10) + (o << 2) + (t & 3)] = acc;
  } else {
    const int b = blk - 6400;
    __shared__ float cs[64];
    if (t < 64) cs[t] = cour[(b << 6) + t];
    __syncthreads();
    float acc = bfused[t];
#pragma unroll 8
    for (int k = 0; k < 64; ++k) acc += Wfused[t * 320 + 256 + k] * cs[k];
    qcour[(b << 8) + t] = acc;
  }
}

// h-part GEMM segment: kk in [K0,K1), accumulates into h00..h13
#define HSEG(K0, K1)                                                      \
  for (int kk = (K0); kk < (K1); ++kk) {                                  \
    const float4 w = *(const float4*)(whb + ((size_t)kk << 10));          \
    const float hv0 = hs[0][(th << 7) + kk];                              \
    const float hv1 = hs[1][(th << 7) + kk];                              \
    h00 += w.x * hv0; h01 += w.y * hv0; h02 += w.z * hv0; h03 += w.w * hv0; \
    h10 += w.x * hv1; h11 += w.y * hv1; h12 += w.z * hv1; h13 += w.w * hv1; \
  }

// ---------------------------------------------------------------------------
// Barrier-free persistent decoder, wave-specialized:
//  - Waves 8-15 compute next step's h-part gates GEMM (needs only h_t) in 3
//    segments, truly overlapped with waves 0-7 running qg/scores_g/softmax.
//  - x-part GEMM reads x directly from emb[sel] (gather phase eliminated).
//  - qp uses all 1024 threads (2-way l-split, combined in scores_p).
//  - rcp-based tanh/sigmoid. 8 block barriers per step.
// ---------------------------------------------------------------------------
__global__ __launch_bounds__(1024, 4) void decoder_loop_k(
    const float* __restrict__ dec, const float* __restrict__ h0,
    const float* __restrict__ c0, const float* __restrict__ emb,
    const float* __restrict__ WcatT, const float* __restrict__ bcat,
    const float* __restrict__ e2g, const float* __restrict__ e2p,
    const float* __restrict__ Eg2, const float* __restrict__ Wq1T4,
    const float* __restrict__ qcour, const float* __restrict__ vg,
    const float* __restrict__ vp, float* __restrict__ out_logp,
    float* __restrict__ out_sel)
{
  const int t_ = threadIdx.x;
  const int b0 = blockIdx.x << 1;
  const int tk = t_ >> 8, tc = t_ & 255;          // x-GEMM: 4 K-chunks x 256 units
  const int wv = t_ >> 6, lane = t_ & 63;
  const int rowS = wv >> 2, lbaseS = (wv & 3) << 4; // score mapping (waves 0-7)
  const int th = (t_ >> 8) & 1, hc = t_ & 255;    // h-GEMM mapping (waves 8-15)

  __shared__ __align__(16) float hs[2][256];
  __shared__ __align__(16) float qcs[2][256];
  __shared__ __align__(16) float bcs[1024];
  __shared__ __align__(16) float vgs[256], vps[256];
  __shared__ __align__(16) float qgs[2][256];
  __shared__ __align__(16) float qpp[2][2][256];  // [lhalf][row][o]
  __shared__ float us[2][64], ps[2][64];
  __shared__ __align__(16) float redX[8][256][4]; // x-part partials [(tk<<1)|r]
  __shared__ __align__(16) float redH[4][256][4]; // h-part partials [(th<<1)|r]
  __shared__ unsigned long long mlds[2];
  __shared__ int selLds[2];

  // ---- init ----
  if (t_ < 512) {
    const int r = t_ >> 8, i = t_ & 255;
    hs[r][i]  = h0[((b0 + r) << 8) + i];
    qcs[r][i] = qcour[((b0 + r) << 8) + i];
  } else if (t_ < 768) {
    vgs[t_ & 255] = vg[t_ & 255];
  } else {
    vps[t_ & 255] = vp[t_ & 255];
  }
  bcs[t_] = bcat[t_];
  float c_reg = (t_ < 512) ? c0[((b0 + (t_ >> 8)) << 8) + (t_ & 255)] : 0.f;
  if (t_ == 0) { mlds[0] = 0ULL; mlds[1] = 0ULL; selLds[0] = 0; selLds[1] = 0; }
  __syncthreads();

  const float* whb = WcatT + ((size_t)(256 + (th << 7)) << 10) + (hc << 2);

  // ---- pre-loop: h-part partials for h0 (waves 8-15) ----
  if (t_ >= 512) {
    float h00 = 0.f, h01 = 0.f, h02 = 0.f, h03 = 0.f;
    float h10 = 0.f, h11 = 0.f, h12 = 0.f, h13 = 0.f;
    HSEG(0, 128)
    *(float4*)&redH[(th << 1) | 0][hc][0] = make_float4(h00, h01, h02, h03);
    *(float4*)&redH[(th << 1) | 1][hc][0] = make_float4(h10, h11, h12, h13);
  }
  __syncthreads();

  for (int step = 0; step < 64; ++step) {
    // ===== A: x-part gates GEMM (all 1024 threads; x direct from dec/emb) ===
    {
      const float* xr0 = (step == 0) ? (dec + ((size_t)b0 << 8))
          : (emb + ((((size_t)selLds[0] << 9) + b0) << 8));
      const float* xr1 = (step == 0) ? (dec + ((size_t)(b0 + 1) << 8))
          : (emb + ((((size_t)selLds[1] << 9) + b0 + 1) << 8));
      const float* wb  = WcatT + ((size_t)(tk << 6) << 10) + (tc << 2);
      const float* x0p = xr0 + (tk << 6);
      const float* x1p = xr1 + (tk << 6);
      float a00 = 0.f, a01 = 0.f, a02 = 0.f, a03 = 0.f;
      float a10 = 0.f, a11 = 0.f, a12 = 0.f, a13 = 0.f;
#pragma unroll 8
      for (int kk = 0; kk < 64; kk += 2) {
        const float2 x0 = *(const float2*)(x0p + kk);
        const float2 x1 = *(const float2*)(x1p + kk);
        const float4 w0 = *(const float4*)(wb + ((size_t)kk << 10));
        const float4 w1 = *(const float4*)(wb + ((size_t)(kk + 1) << 10));
        a00 += w0.x * x0.x; a01 += w0.y * x0.x; a02 += w0.z * x0.x; a03 += w0.w * x0.x;
        a10 += w0.x * x1.x; a11 += w0.y * x1.x; a12 += w0.z * x1.x; a13 += w0.w * x1.x;
        a00 += w1.x * x0.y; a01 += w1.y * x0.y; a02 += w1.z * x0.y; a03 += w1.w * x0.y;
        a10 += w1.x * x1.y; a11 += w1.y * x1.y; a12 += w1.z * x1.y; a13 += w1.w * x1.y;
      }
      *(float4*)&redX[(tk << 1) | 0][tc][0] = make_float4(a00, a01, a02, a03);
      *(float4*)&redX[(tk << 1) | 1][tc][0] = make_float4(a10, a11, a12, a13);
    }
    __syncthreads();                                        // B1

    // ===== LSTM epilogue (512 threads: one (row,unit) each) =================
    if (t_ < 512) {
      const int r = t_ >> 8, u = t_ & 255;
      const float4 b4  = *(const float4*)&bcs[u << 2];
      const float4 xp0 = *(const float4*)&redX[0 + r][u][0];
      const float4 xp1 = *(const float4*)&redX[2 + r][u][0];
      const float4 xp2 = *(const float4*)&redX[4 + r][u][0];
      const float4 xp3 = *(const float4*)&redX[6 + r][u][0];
      const float4 hp0 = *(const float4*)&redH[0 + r][u][0];
      const float4 hp1 = *(const float4*)&redH[2 + r][u][0];
      const float gi = (((xp0.x + xp1.x) + xp2.x) + xp3.x) + (hp0.x + hp1.x) + b4.x;
      const float gf = (((xp0.y + xp1.y) + xp2.y) + xp3.y) + (hp0.y + hp1.y) + b4.y;
      const float gg = (((xp0.z + xp1.z) + xp2.z) + xp3.z) + (hp0.z + hp1.z) + b4.z;
      const float go = (((xp0.w + xp1.w) + xp2.w) + xp3.w) + (hp0.w + hp1.w) + b4.w;
      c_reg = fsigm(gf) * c_reg + fsigm(gi) * ftanh(gg);
      hs[r][u] = fsigm(go) * ftanh(c_reg);
    }
    __syncthreads();                                        // B2 (h_t ready)

    // h-part accumulators for NEXT step (waves 8-15), live across B3..B5
    float h00 = 0.f, h01 = 0.f, h02 = 0.f, h03 = 0.f;
    float h10 = 0.f, h11 = 0.f, h12 = 0.f, h13 = 0.f;

    // ===== P1: qg (waves 0-7) || h-GEMM seg 1 (waves 8-15) ==================
    if (t_ < 512) {
      const int r = t_ >> 8, o = t_ & 255;
      float q = qcs[r][o];
      const float4* wp = (const float4*)Wq1T4 + o;
#pragma unroll 8
      for (int kc = 0; kc < 64; ++kc) {
        const float4 w4 = wp[kc << 8];
        const float4 h4 = *(const float4*)&hs[r][kc << 2];
        q += w4.x * h4.x + w4.y * h4.y + w4.z * h4.z + w4.w * h4.w;
      }
      qgs[r][o] = q;
    } else {
      HSEG(0, 43)
    }
    __syncthreads();                                        // B3

    // ===== P2: scores_g (waves 0-7) || h-GEMM seg 2 =========================
    if (t_ < 512) {
      const float4 q4 = *(const float4*)&qgs[rowS][lane << 2];
      const float4 v4 = *(const float4*)&vgs[lane << 2];
      const unsigned long long mm = mlds[rowS];
      const float* eb = e2g + ((size_t)(b0 + rowS) << 14) + (lane << 2);
#pragma unroll 4
      for (int li = 0; li < 16; ++li) {
        const int l = lbaseS + li;
        const float4 e4 = *(const float4*)(eb + (l << 8));
        float s = v4.x * ftanh(q4.x + e4.x) + v4.y * ftanh(q4.y + e4.y)
                + v4.z * ftanh(q4.z + e4.z) + v4.w * ftanh(q4.w + e4.w);
#pragma unroll
        for (int off = 32; off; off >>= 1) s += __shfl_xor(s, off, 64);
        if (lane == 0) us[rowS][l] = ((mm >> l) & 1ULL) ? NEGV : s;
      }
    } else {
      HSEG(43, 86)
    }
    __syncthreads();                                        // B4

    // ===== P3: softmax_g (t<128) || h-GEMM seg 3 + redH store ===============
    if (t_ < 128) {
      const int row = t_ >> 6;
      const float xv = us[row][lane];
      float mx = xv;
#pragma unroll
      for (int off = 32; off; off >>= 1) mx = fmaxf(mx, __shfl_xor(mx, off, 64));
      const float ev = __expf(xv - mx);
      float sum = ev;
#pragma unroll
      for (int off = 32; off; off >>= 1) sum += __shfl_xor(sum, off, 64);
      ps[row][lane] = ev * frcp(sum);
    } else if (t_ >= 512) {
      HSEG(86, 128)
      *(float4*)&redH[(th << 1) | 0][hc][0] = make_float4(h00, h01, h02, h03);
      *(float4*)&redH[(th << 1) | 1][hc][0] = make_float4(h10, h11, h12, h13);
    }
    __syncthreads();                                        // B5

    // ===== P4: qp partials (all 1024 threads; 2-way l-split) ================
    {
      const int lh = t_ >> 9, r = (t_ >> 8) & 1, o = t_ & 255;
      const float* ec = Eg2 + ((size_t)(b0 + r) << 14) + ((size_t)(lh << 5) << 8) + o;
      float aq = 0.f;
#pragma unroll 8
      for (int l = 0; l < 32; ++l) aq += ps[r][(lh << 5) + l] * ec[l << 8];
      qpp[lh][r][o] = aq;
    }
    __syncthreads();                                        // B6

    // ===== P5: scores_p (waves 0-7; qp combined inline) =====================
    if (t_ < 512) {
      const float4 qa = *(const float4*)&qpp[0][rowS][lane << 2];
      const float4 qb = *(const float4*)&qpp[1][rowS][lane << 2];
      const float4 v4 = *(const float4*)&vps[lane << 2];
      const float qx = qa.x + qb.x, qy = qa.y + qb.y;
      const float qz = qa.z + qb.z, qw = qa.w + qb.w;
      const unsigned long long mm = mlds[rowS];
      const float* eb = e2p + ((size_t)(b0 + rowS) << 14) + (lane << 2);
#pragma unroll 4
      for (int li = 0; li < 16; ++li) {
        const int l = lbaseS + li;
        const float4 e4 = *(const float4*)(eb + (l << 8));
        float s = v4.x * ftanh(qx + e4.x) + v4.y * ftanh(qy + e4.y)
                + v4.z * ftanh(qz + e4.z) + v4.w * ftanh(qw + e4.w);
#pragma unroll
        for (int off = 32; off; off >>= 1) s += __shfl_xor(s, off, 64);
        if (lane == 0) us[rowS][l] = ((mm >> l) & 1ULL) ? NEGV : 10.0f * ftanh(s);
      }
    }
    __syncthreads();                                        // B7

    // ===== P6: log-softmax, argmax, outputs, mask/sel for next step =========
    if (t_ < 128) {
      const int row = t_ >> 6;
      const float xv = us[row][lane];
      float mx = xv;
#pragma unroll
      for (int off = 32; off; off >>= 1) mx = fmaxf(mx, __shfl_xor(mx, off, 64));
      const float sh = xv - mx;
      const float ev = __expf(sh);
      float sum = ev;
#pragma unroll
      for (int off = 32; off; off >>= 1) sum += __shfl_xor(sum, off, 64);
      const float lp = sh - __logf(sum);
      out_logp[((size_t)(b0 + row) << 12) + (step << 6) + lane] = lp;
      float bv = lp; int bi = lane;
#pragma unroll
      for (int off = 32; off; off >>= 1) {
        const float ov = __shfl_xor(bv, off, 64);
        const int   oi = __shfl_xor(bi, off, 64);
        if (ov > bv || (ov == bv && oi < bi)) { bv = ov; bi = oi; }
      }
      if (lane == 0) {
        selLds[row] = bi;
        out_sel[((b0 + row) << 6) + step] = (float)bi;
        unsigned long long m = mlds[row];
        m |= (1ULL << bi);
        if (m == ~0ULL) m &= ~(1ULL << 63);
        mlds[row] = m;
      }
    }
    __syncthreads();                                        // B8
  }
}

// ---------------------------------------------------------------------------
extern "C" void kernel_launch(void* const* d_in, const int* in_sizes, int n_in,
                              void* d_out, int out_size, void* d_ws, size_t ws_size,
                              hipStream_t stream)
{
  const float* dec   = (const float*)d_in[0];
  const float* emb   = (const float*)d_in[1];
  const float* h0    = (const float*)d_in[2];
  const float* c0    = (const float*)d_in[3];
  const float* ctxin = (const float*)d_in[4];
  const float* cour  = (const float*)d_in[5];
  const float* Wih   = (const float*)d_in[7];
  const float* Whh   = (const float*)d_in[8];
  const float* bih   = (const float*)d_in[9];
  const float* bhh   = (const float*)d_in[10];
  const float* Wm    = (const float*)d_in[11];
  const float* bm    = (const float*)d_in[12];
  const float* Wqp   = (const float*)d_in[13];
  const float* bqp   = (const float*)d_in[14];
  const float* Wrp   = (const float*)d_in[15];
  const float* brp   = (const float*)d_in[16];
  const float* vp    = (const float*)d_in[17];
  const float* Wqg   = (const float*)d_in[18];
  const float* bqg   = (const float*)d_in[19];
  const float* Wrg   = (const float*)d_in[20];
  const float* brg   = (const float*)d_in[21];
  const float* vg    = (const float*)d_in[22];

  float* ws = (float*)d_ws;
  float* e2g    = ws + 0;         // [B][L][H] 8388608
  float* e2p    = ws + 8388608;   // 8388608
  float* Eg2    = ws + 16777216;  // 8388608
  float* WcatT  = ws + 25165824;  // [K=512][N=1024] 524288
  float* bcat   = ws + 25690112;  // 1024
  float* Wfused = ws + 25691136;  // 81920
  float* bfused = ws + 25773056;  // 256
  float* Wq1T4  = ws + 25773312;  // 65536
  float* qcour  = ws + 25838848;  // 131072
  float* Wgp    = ws + 25969920;  // 65536
  float* bgp    = ws + 26035456;  // 256

  float* out_logp = (float*)d_out;            // [B][64][64]
  float* out_sel  = (float*)d_out + 2097152;  // [B][64]

  prep1_k<<<2625, 256, 0, stream>>>(Wih, Whh, bih, bhh, Wqg, Wm, bm, bqg,
                                    Wqp, Wrg, brg, bqp,
                                    WcatT, bcat, Wfused, bfused, Wgp, bgp);
  prep2_k<<<6912, 256, 0, stream>>>(ctxin, Wrg, brg, Wrp, brp, Wgp, bgp,
                                    Wqg, Wm, Wfused, bfused, cour,
                                    e2g, e2p, Eg2, Wq1T4, qcour);
  decoder_loop_k<<<256, 1024, 0, stream>>>(dec, h0, c0, emb, WcatT, bcat,
                                           e2g, e2p, Eg2, Wq1T4, qcour,
                                           vg, vp, out_logp, out_sel);
}